// Round 9
// baseline (1352.336 us; speedup 1.0000x reference)
//
#include <hip/hip_runtime.h>
#include <stdint.h>
#include <stddef.h>

#define VOCAB 41
#define EMB   512
#define HID   1024
#define H3    3072
#define BB    128
#define TT    256
#define BT    (BB*TT)
#define NSLOT 8
#define SLOT_U64 32768        // 256 KB per slot

typedef unsigned short u16;
typedef _Float16 half_t;
typedef half_t f16x8 __attribute__((ext_vector_type(8)));
typedef float f32x4 __attribute__((ext_vector_type(4)));
typedef unsigned long long u64;
typedef u64 u64x2 __attribute__((ext_vector_type(2)));

__device__ __forceinline__ float bf2f(u16 u) {
  return __uint_as_float(((uint32_t)u) << 16);
}
__device__ __forceinline__ u16 f2bf(float f) {
  uint32_t x = __float_as_uint(f);
  return (u16)((x + 0x7FFFu + ((x >> 16) & 1u)) >> 16);
}
__device__ __forceinline__ u16 f2h_bits(float f) {
  half_t h = (half_t)f;
  return __builtin_bit_cast(u16, h);
}
__device__ __forceinline__ float sigmoidf_(float x) {
  return 1.0f / (1.0f + __expf(-x));
}
__device__ __forceinline__ float tanh_fast(float x) {
  return 1.0f - 2.0f / (__expf(2.0f * x) + 1.0f);
}
__device__ __forceinline__ u64 aload64(const u64* p) {
  return __hip_atomic_load(p, __ATOMIC_RELAXED, __HIP_MEMORY_SCOPE_AGENT);
}
__device__ __forceinline__ void astore64(u64* p, u64 v) {
  __hip_atomic_store(p, v, __ATOMIC_RELAXED, __HIP_MEMORY_SCOPE_AGENT);
}

// ---------- prologue kernels (r8-identical) ----------

__global__ void detect_kernel(const u16* __restrict__ raw, int* __restrict__ flag) {
  __shared__ int s[256];
  int tid = threadIdx.x, cnt = 0;
  for (int i = tid; i < 4096; i += 256) {
    int e = (raw[i] >> 7) & 0xFF;
    if (e >= 132) cnt++;
  }
  s[tid] = cnt; __syncthreads();
  if (tid == 0) {
    int tot = 0;
    for (int i = 0; i < 256; i++) tot += s[i];
    *flag = (tot > 4) ? 1 : 0;
  }
}

__global__ void conv_kernel(const void* __restrict__ src, float* __restrict__ dst,
                            int n, const int* __restrict__ flag) {
  int i = blockIdx.x * 256 + threadIdx.x;
  if (i >= n) return;
  if (*flag) dst[i] = ((const float*)src)[i];
  else       dst[i] = bf2f(((const u16*)src)[i]);
}

__global__ void tokm_kernel(const int* __restrict__ x,
                            const unsigned char* __restrict__ m,
                            int* __restrict__ tokm) {
  int i = blockIdx.x * 256 + threadIdx.x;
  unsigned char b0 = m[0], b1 = m[1];
  bool t;
  if (b0 == 1) {
    if (b1 != 0) t = (m[i] != 0);
    else         t = (((const int*)m)[i] != 0);
  } else if (b0 == 0x80) {
    t = (((const u16*)m)[i] != 0);
  } else {
    t = (((const float*)m)[i] != 0.0f);
  }
  tokm[i] = x[i] | (t ? 0 : 0x80000000);
}

__global__ __launch_bounds__(256) void proj_kernel(
    const void* __restrict__ emb, const void* __restrict__ gk,
    const float* __restrict__ gbf, float* __restrict__ P,
    const int* __restrict__ flag) {
  int v = blockIdx.x / (H3 / 256);
  int j = (blockIdx.x % (H3 / 256)) * 256 + threadIdx.x;
  float acc = gbf[j];
  if (*flag) {
    const float* e = (const float*)emb + v * EMB;
    const float* g = (const float*)gk;
    for (int k = 0; k < EMB; ++k) acc = fmaf(e[k], g[k * H3 + j], acc);
  } else {
    const u16* e = (const u16*)emb + v * EMB;
    const u16* g = (const u16*)gk;
    for (int k = 0; k < EMB; ++k) acc = fmaf(bf2f(e[k]), bf2f(g[k * H3 + j]), acc);
  }
  P[v * H3 + j] = acc;
}

__global__ void p2_kernel(const float* __restrict__ P, const float* __restrict__ gbf,
                          float* __restrict__ P2) {
  int gc = blockIdx.x;
  int v = threadIdx.x;
  if (v >= VOCAB) return;
  float val = P[v * H3 + gc];
  if (gc < 2048) val += gbf[H3 + gc];
  P2[gc * VOCAB + v] = val;
}

__global__ void pack_wimg_kernel(const void* __restrict__ src, u16* __restrict__ img,
                                 const int* __restrict__ flag) {
  int idx = blockIdx.x * 256 + threadIdx.x;
  int j = idx & 7;
  int t1 = idx >> 3;
  int lane = t1 & 63;
  int t2 = t1 >> 6;
  int g = t2 % 3;
  int t3 = t2 / 3;
  int ks = t3 & 31;
  int ds = t3 >> 5;
  int k = ks * 32 + (lane >> 4) * 8 + j;
  int col = g * 1024 + ds * 16 + (lane & 15);
  float val;
  if (*flag) val = ((const float*)src)[(size_t)k * H3 + col];
  else       val = bf2f(((const u16*)src)[(size_t)k * H3 + col]);
  img[idx] = f2h_bits(val);
}

__global__ void pack_dimg_kernel(const void* __restrict__ src, u16* __restrict__ img,
                                 const int* __restrict__ flag) {
  int idx = blockIdx.x * 256 + threadIdx.x;
  int j = idx & 7;
  int t1 = idx >> 3;
  int lane = t1 & 63;
  int t2 = t1 >> 6;
  int ct = t2 % 3;
  int ks = t2 / 3;
  int k = ks * 32 + (lane >> 4) * 8 + j;
  int v = ct * 16 + (lane & 15);
  float val = 0.0f;
  if (v < VOCAB) {
    if (*flag) val = ((const float*)src)[(size_t)k * VOCAB + v];
    else       val = bf2f(((const u16*)src)[(size_t)k * VOCAB + v]);
  }
  img[idx] = f2h_bits(val);
}

// ---------- persistent GRU: parity-tagged exchange (no flags, no drains) --
// 512 blocks x 256 thr (2/CU). bid = ds*8 + gt. Block: 16 rows (gt) x
// 16 dims (ds), K split across 4 waves; W frags persistent in regs.
// Each exchanged u64 carries a 1-bit generation tag ((t>>3)&1) in its LSB
// (1 ulp of one f16 h value). Consumers poll their own A-data until every
// u64 is tagged fresh -- signal and payload are the same bits, collapsing
// the per-step cross-block chain to ~2 memory round trips.
__global__ __launch_bounds__(256, 2) void gru_persist(
    const uint4* __restrict__ Wimg, const int* __restrict__ tokm,
    const float* __restrict__ P2, const float* __restrict__ gbf,
    u64* __restrict__ exch, u16* __restrict__ Hout) {
  int bid = blockIdx.x;
  int gt = bid & 7, ds = bid >> 3;
  int tid = threadIdx.x;
  int w = tid >> 6, lane = tid & 63;

  __shared__ float red[4][64][13];
  __shared__ u16 tr[256];
  __shared__ float Pl[3][16][49];
  __shared__ int tokL[16 * 256];

  // persistent B fragments: 3 gates x 8 k-steps (this wave's K-quarter)
  f16x8 breg[3][8];
  {
    const uint4* wsrc = Wimg + (size_t)ds * 96 * 64 + lane;
    #pragma unroll
    for (int k8 = 0; k8 < 8; ++k8)
      #pragma unroll
      for (int g = 0; g < 3; ++g)
        breg[g][k8] = __builtin_bit_cast(f16x8, wsrc[((w * 8 + k8) * 3 + g) * 64]);
  }

  // preload epilogue tables: P2 slice (3x16x41) and token map (16x256)
  for (int i = tid; i < 3 * 16 * VOCAB; i += 256) {
    int v = i % VOCAB;
    int t1 = i / VOCAB;
    int di = t1 & 15, g = t1 >> 4;
    Pl[g][di][v] = P2[(size_t)(g * 1024 + ds * 16 + di) * VOCAB + v];
  }
  for (int i = tid; i < 1024; i += 256)
    ((uint4*)tokL)[i] = ((const uint4*)tokm)[gt * 1024 + i];

  // per-thread epilogue ownership: one (row, dim) pair
  int row = tid >> 4, dim = tid & 15;
  int lane_src = (row >> 2) * 16 + dim;
  int rg = row & 3;
  float b1h = gbf[H3 + 2048 + ds * 16 + dim];
  float hcur = 0.f;
  int ks_blk = ds >> 1, q0 = (ds & 1) * 2;
  __syncthreads();

  for (int t = 0; t < TT; ++t) {
    // A loads with embedded-tag gating: poll this wave's K-quarter until
    // every u64 carries generation tag (t>>3)&1.
    u64 av[16];
    {
      u64 etag = (u64)((t >> 3) & 1);
      const u64* abase = exch + (size_t)(t & 7) * SLOT_U64 + gt * 4096 +
                         (w * 8) * 128 + lane * 2;
      int cap = 0;
      while (true) {
        #pragma unroll
        for (int i = 0; i < 8; ++i) {
          av[2 * i]     = aload64(abase + i * 128);
          av[2 * i + 1] = aload64(abase + i * 128 + 1);
        }
        u64 bad = 0;
        #pragma unroll
        for (int i = 0; i < 16; ++i) bad |= (av[i] ^ etag) & 1ULL;
        if (__ballot(bad != 0ULL) == 0ULL) break;
        __builtin_amdgcn_s_sleep(2);
        if (++cap > (1 << 14)) break;   // fail fast instead of hanging
      }
    }

    f32x4 acc0 = {0.f, 0.f, 0.f, 0.f};
    f32x4 acc1 = {0.f, 0.f, 0.f, 0.f};
    f32x4 acc2 = {0.f, 0.f, 0.f, 0.f};
    #pragma unroll
    for (int k8 = 0; k8 < 8; ++k8) {
      u64x2 pair; pair.x = av[2 * k8]; pair.y = av[2 * k8 + 1];
      f16x8 a = __builtin_bit_cast(f16x8, pair);
      acc0 = __builtin_amdgcn_mfma_f32_16x16x32_f16(a, breg[0][k8], acc0, 0, 0, 0);
      acc1 = __builtin_amdgcn_mfma_f32_16x16x32_f16(a, breg[1][k8], acc1, 0, 0, 0);
      acc2 = __builtin_amdgcn_mfma_f32_16x16x32_f16(a, breg[2][k8], acc2, 0, 0, 0);
    }

    {
      float* q = red[w][lane];
      q[0] = acc0[0]; q[1] = acc0[1]; q[2]  = acc0[2]; q[3]  = acc0[3];
      q[4] = acc1[0]; q[5] = acc1[1]; q[6]  = acc1[2]; q[7]  = acc1[3];
      q[8] = acc2[0]; q[9] = acc2[1]; q[10] = acc2[2]; q[11] = acc2[3];
    }
    __syncthreads();                                   // S2

    // per-thread reduce over 4 K-quarters + gate epilogue
    {
      float a0 = 0.f, a1 = 0.f, a2 = 0.f;
      #pragma unroll
      for (int ww = 0; ww < 4; ++ww) {
        const float* q = red[ww][lane_src];
        a0 += q[rg]; a1 += q[4 + rg]; a2 += q[8 + rg];
      }
      int tm = tokL[row * 256 + t];
      int tok = tm & 0xFFFF;
      float z  = sigmoidf_(Pl[0][dim][tok] + a0);
      float r_ = sigmoidf_(Pl[1][dim][tok] + a1);
      float hh = tanh_fast(Pl[2][dim][tok] + r_ * (a2 + b1h));
      if (tm >= 0) hcur = z * hcur + (1.0f - z) * hh;
      tr[(dim >> 3) * 128 + row * 8 + (dim & 7)] = f2h_bits(hcur);
    }
    __syncthreads();                                   // S3

    if (w == 0) {
      u64 ntag = (u64)(((t + 1) >> 3) & 1);
      u64 v = ((const u64*)tr)[lane];
      v = (v & ~1ULL) | ntag;                          // embed generation tag
      astore64(exch + (size_t)((t + 1) & 7) * SLOT_U64 + gt * 4096 +
                   ks_blk * 128 + q0 * 32 + lane, v);
      // Hout store off the critical path (visible at kernel completion)
      if (lane < 32) {
        int qq = lane >> 4, mm = lane & 15;
        uint4 hv = ((const uint4*)tr)[lane];
        int b = gt * 16 + mm;
        size_t idx = ((size_t)(b * 16 + (t >> 4)) * 32 + ks_blk) * 64 +
                     (q0 + qq) * 16 + (t & 15);
        ((uint4*)Hout)[idx] = hv;
      }
    }
  }
}

// ---------- dense epilogue (r8-identical) ----------
__global__ __launch_bounds__(256) void dense_mfma(
    const u16* __restrict__ HoutImg, const uint4* __restrict__ dimg,
    const float* __restrict__ dbf, void* __restrict__ out,
    const int* __restrict__ flag) {
  __shared__ uint4 Bl[48 * 64];
  int tid = threadIdx.x;
  int w = tid >> 6, lane = tid & 63;
  int quad = lane >> 4, vi = lane & 15;
  int gt0 = blockIdx.x * 8 + w * 2;

  f32x4 acc[2][3];
  #pragma unroll
  for (int i = 0; i < 2; ++i)
    #pragma unroll
    for (int c = 0; c < 3; ++c) acc[i][c] = (f32x4){0.f, 0.f, 0.f, 0.f};

  for (int half = 0; half < 2; ++half) {
    for (int i = tid; i < 48 * 64; i += 256) Bl[i] = dimg[half * 48 * 64 + i];
    __syncthreads();
    #pragma unroll
    for (int ks16 = 0; ks16 < 16; ++ks16) {
      int ks = half * 16 + ks16;
      f16x8 a0 = __builtin_bit_cast(
          f16x8, ((const uint4*)HoutImg)[((size_t)gt0 * 32 + ks) * 64 + lane]);
      f16x8 a1 = __builtin_bit_cast(
          f16x8, ((const uint4*)HoutImg)[(((size_t)gt0 + 1) * 32 + ks) * 64 + lane]);
      #pragma unroll
      for (int c = 0; c < 3; ++c) {
        f16x8 bf = __builtin_bit_cast(f16x8, Bl[(ks16 * 3 + c) * 64 + lane]);
        acc[0][c] = __builtin_amdgcn_mfma_f32_16x16x32_f16(a0, bf, acc[0][c], 0, 0, 0);
        acc[1][c] = __builtin_amdgcn_mfma_f32_16x16x32_f16(a1, bf, acc[1][c], 0, 0, 0);
      }
    }
    __syncthreads();
  }

  int isf = *flag;
  #pragma unroll
  for (int i = 0; i < 2; ++i) {
    #pragma unroll
    for (int c = 0; c < 3; ++c) {
      int v = c * 16 + vi;
      if (v >= VOCAB) continue;
      float bias = dbf[v];
      #pragma unroll
      for (int rg = 0; rg < 4; ++rg) {
        size_t bt = (size_t)(gt0 + i) * 16 + quad * 4 + rg;
        float val = acc[i][c][rg] + bias;
        if (isf) ((float*)out)[bt * VOCAB + v] = val;
        else     ((u16*)out)[bt * VOCAB + v] = f2bf(val);
      }
    }
  }
}

// ---------- launch ----------

extern "C" void kernel_launch(void* const* d_in, const int* in_sizes, int n_in,
                              void* d_out, int out_size, void* d_ws, size_t ws_size,
                              hipStream_t stream) {
  const int* x            = (const int*)d_in[0];
  const unsigned char* mk = (const unsigned char*)d_in[1];

  char* ws = (char*)d_ws;
  int*   flag  = (int*)(ws + 0);
  float* dbf   = (float*)(ws + 4 * 1024);
  float* gbf   = (float*)(ws + 8 * 1024);            // 24 KB
  int*   tokm  = (int*)(ws + 64 * 1024);             // 128 KB
  u16*   dimg  = (u16*)(ws + 192 * 1024);            // 96 KB
  float* P     = (float*)(ws + 288 * 1024);          // 504 KB
  float* P2    = (float*)(ws + 800 * 1024);          // 504 KB
  u64*   exch  = (u64*)(ws + 1312 * 1024);           // 2 MB (8 slots x 256 KB)
  u16*   Wimg  = (u16*)(ws + 3456 * 1024);           // 6 MB
  u16*   Hout  = (u16*)(ws + 10 * 1024 * 1024);      // 64 MB

  detect_kernel<<<1, 256, 0, stream>>>((const u16*)d_in[4], flag);
  conv_kernel<<<(2 * H3 + 255) / 256, 256, 0, stream>>>(d_in[5], gbf, 2 * H3, flag);
  conv_kernel<<<1, 256, 0, stream>>>(d_in[7], dbf, VOCAB, flag);
  tokm_kernel<<<BT / 256, 256, 0, stream>>>(x, mk, tokm);
  proj_kernel<<<VOCAB * (H3 / 256), 256, 0, stream>>>(d_in[2], d_in[3], gbf, P, flag);
  p2_kernel<<<H3, 64, 0, stream>>>(P, gbf, P2);
  pack_wimg_kernel<<<(64 * 32 * 3 * 64 * 8) / 256, 256, 0, stream>>>(d_in[4], Wimg, flag);
  pack_dimg_kernel<<<(32 * 3 * 64 * 8) / 256, 256, 0, stream>>>(d_in[6], dimg, flag);
  // slot 0 = h_0 = zeros with tag 0 (valid for t=0).
  hipMemsetAsync(exch, 0, SLOT_U64 * 8, stream);
  // slots 1-7 = 0xFF: tag bit 1 = INVALID for their first reads (t=1..7,
  // which expect tag 0). Harness poison 0xAA has LSB 0 and would be
  // falsely accepted -- this memset is correctness-critical per launch.
  hipMemsetAsync((char*)exch + SLOT_U64 * 8, 0xFF, 7 * SLOT_U64 * 8, stream);

  gru_persist<<<512, 256, 0, stream>>>((const uint4*)Wimg, tokm, P2, gbf,
                                       exch, Hout);
  dense_mfma<<<256, 256, 0, stream>>>(Hout, (const uint4*)dimg, dbf, d_out, flag);
}